// Round 3
// baseline (219.992 us; speedup 1.0000x reference)
//
#include <hip/hip_runtime.h>
#include <hip/hip_bf16.h>

#define BB 16
#define NN 64
#define PREVN 6
#define PREDN 30
#define HH 256
#define EE 4032              // NN*(NN-1)
#define EROWS (BB*EE)        // 64512
#define NROWS (BB*NN)        // 1024

typedef short short8 __attribute__((ext_vector_type(8)));
typedef float f32x4 __attribute__((ext_vector_type(4)));

// ---- f32 workspace layout (float element offsets) ----
enum : int {
  OFF_STATS_E = 0,       // [0:256]=sum [256:512]=sumsq (edge MLP)
  OFF_STATS_M = 1024,    // [1024:1280]=sum [1280:1536]=sumsq (node MLP)
  OFF_CNT     = 1536,    // grid-barrier counter (zeroed each launch)
  OFF_XRS     = 2048,    // 262144 f32 slots = 524288 bf16: XR ++ XS
  F32_END     = 264192
};
// ---- bf16 area (element offsets within wb = (bf16*)(ws + F32_END)) ----
// Weight panels in MFMA-fragment order:
//   P[((j*KC + ks)*64 + lane)*8 + e] = W[ks*32 + (lane>>4)*8 + e][j*16 + (lane&15)]
enum : size_t {
  BO_W1TE  = 0,          // 256*512 (n2e W1 panel, KC=16)
  BO_W2TE  = 131072,     // 256*256 (n2e W2 panel, KC=8)
  BO_W1TN  = 196608,     // 256*512 (e2n W1 panel, KC=16)
  BO_W2TN  = 327680,     // 256*256 (e2n W2 panel, KC=8)
  BO_WFT   = 393216,     // 256*512 (W_fuse panel, KC=16)
  BO_WPT   = 524288,     // 64*256  (W_pred panel, KC=8, cols 60..63 zero)
  BO_XG    = 540672,     // 1024*256 raw x (bf16)
  BO_INC   = 802816,     // 1024*256 f32 incraw lives here (as bf16 offset; 1MB)
  BO_E2    = 2113536     // 64512*256 SENDER-major: row = (b*64+send)*63 + jpos
};

// fast ELU: exp(x)-1 via v_exp_f32
__device__ __forceinline__ float eluf(float v) { return v > 0.f ? v : __expf(v) - 1.f; }

// compute one x-embed element: row rr (global), col
__device__ __forceinline__ float xembed(const float* __restrict__ centers,
                                        const float* __restrict__ Wt,
                                        const float* __restrict__ bt,
                                        int rr, int col) {
  const float* c = centers + rr * 12;
  float acc = bt[col];
  #pragma unroll
  for (int t = 0; t < 5; ++t) {
    float dx = c[(t+1)*2 + 0] - c[t*2 + 0];
    float dy = c[(t+1)*2 + 1] - c[t*2 + 1];
    acc += dx * Wt[(2 + 2*t)*HH + col] + dy * Wt[(3 + 2*t)*HH + col];
  }
  return acc;
}

// ================= prep: weight panels + zero stats/incraw + x-embed ===========
struct PrepArgs {
  const float *centers, *W_traj, *b_traj;
  const float *n2e_W1, *n2e_W2, *e2n_W1, *e2n_W2, *W_fuse, *W_pred;
  float* ws;
  float* inc;                      // incraw 1024x256 f32
  __hip_bfloat16 *p1e, *p2e, *p1n, *p2n, *pf, *pp, *xg;
};

__global__ __launch_bounds__(256) void k_prep(PrepArgs a) {
  const int bid = blockIdx.x, tid = threadIdx.x;
  if (bid < 264) {                 // weight panels, 4 tiles (1KB each) per block
    const float* W; __hip_bfloat16* P; int ksh, t0, pad = 0;
    if (bid < 64)       { W = a.n2e_W1; P = a.p1e; ksh = 4; t0 = bid*4; }
    else if (bid < 96)  { W = a.n2e_W2; P = a.p2e; ksh = 3; t0 = (bid-64)*4; }
    else if (bid < 160) { W = a.e2n_W1; P = a.p1n; ksh = 4; t0 = (bid-96)*4; }
    else if (bid < 192) { W = a.e2n_W2; P = a.p2n; ksh = 3; t0 = (bid-160)*4; }
    else if (bid < 256) { W = a.W_fuse; P = a.pf;  ksh = 4; t0 = (bid-192)*4; }
    else                { W = a.W_pred; P = a.pp;  ksh = 3; t0 = (bid-256)*4; pad = 1; }
    const int l = tid & 63, sub = tid >> 6;
    const int t = t0 + sub;
    const int j = t >> ksh, ks = t & ((1 << ksh) - 1);
    const int m16 = l & 15, q = l >> 4;
    __hip_bfloat16* dst = P + ((size_t)t*64 + l)*8;
    if (!pad) {
      const float* src = W + (size_t)(ks*32 + q*8)*256 + j*16 + m16;
      #pragma unroll
      for (int e = 0; e < 8; ++e)
        dst[e] = __float2bfloat16(src[(size_t)e*256]);
    } else {
      const int col = j*16 + m16;
      #pragma unroll
      for (int e = 0; e < 8; ++e)
        dst[e] = __float2bfloat16(col < 60 ?
                     W[(size_t)(ks*32 + q*8 + e)*60 + col] : 0.f);
    }
  } else if (bid < 272) {
    a.ws[(bid - 264) * 256 + tid] = 0.f;   // zero stats_E, stats_M, cnt
  } else if (bid < 336) {          // x-embed: 16 rows per block
    int row0 = (bid - 272) * 16;
    #pragma unroll
    for (int r = 0; r < 16; ++r)
      a.xg[(size_t)(row0 + r)*256 + tid] =
          __float2bfloat16(xembed(a.centers, a.W_traj, a.b_traj, row0 + r, tid));
  } else {                         // zero incraw: 64 blocks x 4096 floats
    float* p = a.inc + (size_t)(bid - 336) * 4096;
    #pragma unroll
    for (int i = 0; i < 4; ++i)
      *reinterpret_cast<float4*>(p + (i*256 + tid)*4) = (float4){0.f,0.f,0.f,0.f};
  }
}

// ---- XR/XS = xg @ W1_{top,bot}: single-wave pure GEMM, grid 512 ----
__global__ __launch_bounds__(64) void k_xrs2(
    const __hip_bfloat16* __restrict__ xg,    // 1024 x 256
    const __hip_bfloat16* __restrict__ W1P,   // panel KC=16
    const float* __restrict__ b1,
    __hip_bfloat16* __restrict__ xrs) {       // XR ++ XS
  const int lane = threadIdx.x;
  const int m16 = lane & 15, quad = lane >> 4;
  const int ko = quad * 8;
  const int rt = blockIdx.x >> 3, s = blockIdx.x & 7;
  const int half = s >> 2, j0 = (s & 3) * 64;
  const int jg0 = (s & 3) * 4;
  const int row0 = rt * 16;
  __hip_bfloat16* dst = xrs + (size_t)half * 262144;

  f32x4 acc[4];
  #pragma unroll
  for (int jt = 0; jt < 4; ++jt) {
    float bv = half ? 0.f : b1[j0 + jt*16 + m16];
    acc[jt] = (f32x4){bv, bv, bv, bv};
  }
  #pragma unroll
  for (int ks = 0; ks < 8; ++ks) {
    short8 af = *reinterpret_cast<const short8*>(
        xg + (size_t)(row0 + m16)*256 + ks*32 + ko);
    short8 bf[4];
    #pragma unroll
    for (int jt = 0; jt < 4; ++jt)
      bf[jt] = *reinterpret_cast<const short8*>(
          W1P + (((size_t)(jg0 + jt)*16 + half*8 + ks)*64 + lane)*8);
    #pragma unroll
    for (int jt = 0; jt < 4; ++jt)
      acc[jt] = __builtin_amdgcn_mfma_f32_16x16x32_bf16(af, bf[jt], acc[jt], 0, 0, 0);
  }
  #pragma unroll
  for (int jt = 0; jt < 4; ++jt)
    #pragma unroll
    for (int r = 0; r < 4; ++r)
      dst[(size_t)(row0 + quad*4 + r)*256 + j0 + jt*16 + m16] =
          __float2bfloat16(acc[jt][r]);
}

// ================= edge MLP: fused receiver-sum, sender-major writeout =========
__global__ __launch_bounds__(256, 4) void k_mlp8(
    const __hip_bfloat16* __restrict__ xrs,   // XR ++ XS
    const __hip_bfloat16* __restrict__ W2P,   // panel KC=8
    const float* __restrict__ b2,
    __hip_bfloat16* __restrict__ outp,        // e2 sender-major
    float* __restrict__ stats,                // [0:256]=sum [256:512]=sumsq
    float* __restrict__ incraw) {             // 1024 x 256 f32 raw receiver sums
  __shared__ alignas(16) __hip_bfloat16 h1s[64][264];
  __shared__ float sst[3][256];               // s0 (recv n0), s1 (recv n0+1), sumsq
  const int tid = threadIdx.x;
  const int w = tid >> 6, lane = tid & 63;
  const int m16 = lane & 15, quad = lane >> 4;
  const int ko = quad * 8;
  const int blk = blockIdx.x;                 // 1008
  const int bb = blk / 63, lb = blk - bb*63;
  const int n0 = (lb * 64) / 63;
  const int thr = (n0 + 1) * 63 - lb * 64;    // 1..63
  const int colw = w * 64;

  #pragma unroll
  for (int i = 0; i < 3; ++i) sst[i][tid] = 0.f;

  // ---- h1 = elu(XR[rc] + XS[sd]) -> h1s; 16B vector loads, L2-hot ----
  {
    const int rg = tid >> 5;                  // 0..7
    const int c8 = (tid & 31) * 8;
    const __hip_bfloat16* xrb = xrs + (size_t)(bb*64 + n0)*256 + c8;
    const __hip_bfloat16* xsb = xrs + 262144 + (size_t)bb*64*256 + c8;
    union { uint4 u; __hip_bfloat16 h[8]; } vr0, vr1;
    vr0.u = *reinterpret_cast<const uint4*>(xrb);
    vr1.u = *reinterpret_cast<const uint4*>(xrb + 256);
    #pragma unroll
    for (int i = 0; i < 8; ++i) {
      int r = rg + i*8;
      int isn1 = (r >= thr) ? 1 : 0;
      int rc = n0 + isn1;
      int jj = lb*64 + r - rc*63;
      int sd = jj + (jj >= rc ? 1 : 0);
      union { uint4 u; __hip_bfloat16 h[8]; } vs, va, o;
      vs.u = *reinterpret_cast<const uint4*>(xsb + (size_t)sd*256);
      va.u = isn1 ? vr1.u : vr0.u;
      #pragma unroll
      for (int j = 0; j < 8; ++j)
        o.h[j] = __float2bfloat16(eluf(__bfloat162float(va.h[j]) +
                                       __bfloat162float(vs.h[j])));
      *reinterpret_cast<uint4*>(&h1s[r][c8]) = o.u;
    }
  }
  __syncthreads();

  // ---- layer 2: 64x256 @ 256x256; B from coalesced panel ----
  f32x4 acc2[4][4];
  #pragma unroll
  for (int jt = 0; jt < 4; ++jt) {
    float bv = b2[colw + jt*16 + m16];
    #pragma unroll
    for (int mt = 0; mt < 4; ++mt) acc2[mt][jt] = (f32x4){bv, bv, bv, bv};
  }
  #pragma unroll
  for (int kt = 0; kt < 4; ++kt) {
    #pragma unroll
    for (int ks = 0; ks < 2; ++ks) {
      const int k0 = kt*64 + ks*32 + ko;
      const int chunk = kt*2 + ks;
      short8 af[4], bf[4];
      #pragma unroll
      for (int jt = 0; jt < 4; ++jt)
        bf[jt] = *reinterpret_cast<const short8*>(
            W2P + (((size_t)(w*4 + jt)*8 + chunk)*64 + lane)*8);
      #pragma unroll
      for (int mt = 0; mt < 4; ++mt)
        af[mt] = *(const short8*)((const char*)h1s +
                     (size_t)(mt*16 + m16)*528 + k0*2);
      #pragma unroll
      for (int mt = 0; mt < 4; ++mt)
        #pragma unroll
        for (int jt = 0; jt < 4; ++jt)
          acc2[mt][jt] = __builtin_amdgcn_mfma_f32_16x16x32_bf16(af[mt], bf[jt],
                                                                 acc2[mt][jt], 0, 0, 0);
    }
  }
  __syncthreads();   // all h1 reads done before h1s is overwritten with h2

  // ---- ELU(h2) -> h1s; per-receiver sums + stats from registers ----
  #pragma unroll
  for (int jt = 0; jt < 4; ++jt) {
    float s0 = 0.f, s1 = 0.f, sq = 0.f;
    #pragma unroll
    for (int mt = 0; mt < 4; ++mt)
      #pragma unroll
      for (int r = 0; r < 4; ++r) {
        int row = mt*16 + quad*4 + r;
        float hv = eluf(acc2[mt][jt][r]);
        h1s[row][colw + jt*16 + m16] = __float2bfloat16(hv);
        float t1 = (row >= thr) ? hv : 0.f;
        s1 += t1; s0 += hv - t1;
        sq += hv * hv;
      }
    atomicAdd(&sst[0][colw + jt*16 + m16], s0);
    atomicAdd(&sst[1][colw + jt*16 + m16], s1);
    atomicAdd(&sst[2][colw + jt*16 + m16], sq);
  }
  __syncthreads();

  {
    float s0 = sst[0][tid], s1 = sst[1][tid];
    atomicAdd(&stats[tid], s0 + s1);
    atomicAdd(&stats[256 + tid], sst[2][tid]);
    atomicAdd(&incraw[(size_t)(bb*64 + n0)*256 + tid], s0);
    atomicAdd(&incraw[(size_t)(bb*64 + n0 + 1)*256 + tid], s1);
  }
  // sender-major writeout: row (rc,sd) -> e2[(bb*64+sd)*63 + jpos]
  #pragma unroll
  for (int i = 0; i < 8; ++i) {
    int u = i*256 + tid;
    int r = u >> 5, c = (u & 31) * 8;
    int isn1 = (r >= thr) ? 1 : 0;
    int rc = n0 + isn1;
    int jj = lb*64 + r - rc*63;
    int sd = jj + (jj >= rc ? 1 : 0);
    int jpos = rc - (jj < rc ? 1 : 0);
    *reinterpret_cast<uint4*>(outp + ((size_t)(bb*64 + sd)*63 + jpos)*HH + c) =
        *reinterpret_cast<const uint4*>(&h1s[r][c]);
  }
}

// ================= fused node pipeline: agg+BN + n1 + n2 + BN + hf + pred ======
// 256 blocks x 256 threads, 4 node-rows per block (wave w owns node bn0+w).
// Only cross-block dependency is the 2KB node-BN stats -> one grid barrier.
// All 256 blocks are co-resident by capacity (1 per CU), so the spin is safe.
struct NodeArgs {
  const __hip_bfloat16 *e2;        // sender-major
  const float *incraw;             // 1024x256 raw receiver sums
  const float *stE, *gamE, *betE;  // edge BN
  const __hip_bfloat16 *W1P; const float *b1;   // e2n W1 panel KC=16
  const __hip_bfloat16 *W2P; const float *b2;   // e2n W2 panel KC=8
  float *stM; const float *gamM, *betM;         // node BN
  const __hip_bfloat16 *WfP; const float *bfv;  // fuse panel KC=16
  const __hip_bfloat16 *WpP; const float *bp;   // pred panel KC=8
  const __hip_bfloat16 *xg;
  const float *centers;
  unsigned int *cnt;
  float *out;
};

__global__ __launch_bounds__(256) void k_node(NodeArgs a) {
  __shared__ alignas(16) __hip_bfloat16 nds[16][520];  // nodes tile (rows 4..15 zero)
  __shared__ alignas(16) __hip_bfloat16 h1[16][264];
  __shared__ alignas(16) __hip_bfloat16 m2[16][264];
  __shared__ alignas(16) __hip_bfloat16 fgs[16][264];
  __shared__ float bnv[2][256];                        // BN a / c0 (edge, then node)
  __shared__ float rl[4][68];
  const int tid = threadIdx.x;
  const int w = tid >> 6, lane = tid & 63;
  const int m16 = lane & 15, quad = lane >> 4;
  const int ko = quad * 8;
  const int bn0 = blockIdx.x * 4;

  // edge-BN coefficients (col = tid)
  {
    const float inv = 1.f / (float)EROWS;
    float mean = a.stE[tid] * inv;
    float var  = fmaxf(a.stE[256 + tid] * inv - mean*mean, 0.f);
    float am = a.gamE[tid] * rsqrtf(var + 1e-5f);
    bnv[0][tid] = am;
    bnv[1][tid] = a.betE[tid] - mean * am;
  }
  // zero pad rows 4..15 of nds (rows*520 bf16 from row 4)
  {
    unsigned int* z = reinterpret_cast<unsigned int*>(&nds[4][0]);
    for (int i = tid; i < 12*260; i += 256) z[i] = 0u;
  }

  // ---- phase A: sender aggregation, wave w -> node bn0+w (63 contiguous rows)
  const int rw = lane >> 5, c8 = (lane & 31) * 8;
  float s[8] = {0.f,0.f,0.f,0.f,0.f,0.f,0.f,0.f};
  {
    const __hip_bfloat16* ebase = a.e2 + ((size_t)(bn0 + w) * 63) * HH + c8;
    #pragma unroll 4
    for (int k = 0; k < 32; ++k) {
      int row = rw + 2*k;
      if (row < 63) {
        union { uint4 u; __hip_bfloat16 h[8]; } v;
        v.u = *reinterpret_cast<const uint4*>(ebase + (size_t)row * HH);
        #pragma unroll
        for (int j = 0; j < 8; ++j) s[j] += __bfloat162float(v.h[j]);
      }
    }
    #pragma unroll
    for (int j = 0; j < 8; ++j) s[j] += __shfl_xor(s[j], 32);
  }
  __syncthreads();   // bnv + pad ready
  if (lane < 32) {   // finalize node row bn0+w
    const float* ip = a.incraw + (size_t)(bn0 + w)*256 + c8;
    #pragma unroll
    for (int j = 0; j < 8; ++j) {
      int col = c8 + j;
      float am = bnv[0][col], c0 = bnv[1][col];
      nds[w][col]       = __float2bfloat16(am * (ip[j] * (1.f/63.f)) + c0);
      nds[w][256 + col] = __float2bfloat16(am * (s[j]  * (1.f/63.f)) + c0);
    }
  }
  __syncthreads();

  // ---- phase B: n1 = elu(nodes @ W1 + b1), wave w -> cols w*64..w*64+63 ----
  {
    f32x4 acc[4];
    #pragma unroll
    for (int jt = 0; jt < 4; ++jt) {
      float bv = a.b1[w*64 + jt*16 + m16];
      acc[jt] = (f32x4){bv, bv, bv, bv};
    }
    #pragma unroll
    for (int ks = 0; ks < 16; ++ks) {
      short8 af = *reinterpret_cast<const short8*>(&nds[m16][ks*32 + ko]);
      short8 bf[4];
      #pragma unroll
      for (int jt = 0; jt < 4; ++jt)
        bf[jt] = *reinterpret_cast<const short8*>(
            a.W1P + (((size_t)(w*4 + jt)*16 + ks)*64 + lane)*8);
      #pragma unroll
      for (int jt = 0; jt < 4; ++jt)
        acc[jt] = __builtin_amdgcn_mfma_f32_16x16x32_bf16(af, bf[jt], acc[jt], 0, 0, 0);
    }
    #pragma unroll
    for (int jt = 0; jt < 4; ++jt)
      #pragma unroll
      for (int r = 0; r < 4; ++r)
        h1[quad*4 + r][w*64 + jt*16 + m16] = __float2bfloat16(eluf(acc[jt][r]));
  }
  __syncthreads();

  // ---- phase C: n2 = elu(h1 @ W2 + b2) + node stats (real rows 0..3 only) ----
  {
    f32x4 acc[4];
    #pragma unroll
    for (int jt = 0; jt < 4; ++jt) {
      float bv = a.b2[w*64 + jt*16 + m16];
      acc[jt] = (f32x4){bv, bv, bv, bv};
    }
    #pragma unroll
    for (int ks = 0; ks < 8; ++ks) {
      short8 af = *(const short8*)((const char*)h1 +
                      (size_t)m16*528 + (ks*32 + ko)*2);
      short8 bf[4];
      #pragma unroll
      for (int jt = 0; jt < 4; ++jt)
        bf[jt] = *reinterpret_cast<const short8*>(
            a.W2P + (((size_t)(w*4 + jt)*8 + ks)*64 + lane)*8);
      #pragma unroll
      for (int jt = 0; jt < 4; ++jt)
        acc[jt] = __builtin_amdgcn_mfma_f32_16x16x32_bf16(af, bf[jt], acc[jt], 0, 0, 0);
    }
    #pragma unroll
    for (int jt = 0; jt < 4; ++jt) {
      float ps = 0.f, pq = 0.f;
      #pragma unroll
      for (int r = 0; r < 4; ++r) {
        float hv = eluf(acc[jt][r]);
        m2[quad*4 + r][w*64 + jt*16 + m16] = __float2bfloat16(hv);
        ps += hv; pq += hv * hv;
      }
      if (quad == 0) {   // rows 0..3 are the real rows; unique col per lane
        int col = w*64 + jt*16 + m16;
        atomicAdd(&a.stM[col], ps);
        atomicAdd(&a.stM[256 + col], pq);
      }
    }
  }
  __syncthreads();
  __threadfence();
  // ---- grid barrier: wait for all 256 blocks' stats ----
  if (tid == 0) {
    __hip_atomic_fetch_add(a.cnt, 1u, __ATOMIC_ACQ_REL, __HIP_MEMORY_SCOPE_AGENT);
    while (__hip_atomic_load(a.cnt, __ATOMIC_ACQUIRE, __HIP_MEMORY_SCOPE_AGENT) < 256u)
      __builtin_amdgcn_s_sleep(2);
  }
  __syncthreads();

  // node-BN coefficients (col = tid)
  {
    const float inv = 1.f / (float)NROWS;
    float mean = a.stM[tid] * inv;
    float var  = fmaxf(a.stM[256 + tid] * inv - mean*mean, 0.f);
    float am = a.gamM[tid] * rsqrtf(var + 1e-5f);
    bnv[0][tid] = am;
    bnv[1][tid] = a.betM[tid] - mean * am;
  }
  __syncthreads();

  // ---- phase D: fused = [xg | BN(m2)] @ Wf + bf ----
  {
    f32x4 acc[4];
    #pragma unroll
    for (int jt = 0; jt < 4; ++jt) {
      float bv = a.bfv[w*64 + jt*16 + m16];
      acc[jt] = (f32x4){bv, bv, bv, bv};
    }
    #pragma unroll
    for (int ks = 0; ks < 16; ++ks) {
      short8 af;
      if (ks < 8) {
        af = *reinterpret_cast<const short8*>(
            a.xg + (size_t)(bn0 + m16)*256 + ks*32 + ko);
      } else {
        int k0 = (ks - 8)*32 + ko;
        union { short8 s8; __hip_bfloat16 h[8]; } o;
        #pragma unroll
        for (int j = 0; j < 8; ++j) {
          float mv = __bfloat162float(m2[m16][k0 + j]);
          o.h[j] = __float2bfloat16(bnv[0][k0+j] * mv + bnv[1][k0+j]);
        }
        af = o.s8;
      }
      short8 bf[4];
      #pragma unroll
      for (int jt = 0; jt < 4; ++jt)
        bf[jt] = *reinterpret_cast<const short8*>(
            a.WfP + (((size_t)(w*4 + jt)*16 + ks)*64 + lane)*8);
      #pragma unroll
      for (int jt = 0; jt < 4; ++jt)
        acc[jt] = __builtin_amdgcn_mfma_f32_16x16x32_bf16(af, bf[jt], acc[jt], 0, 0, 0);
    }
    #pragma unroll
    for (int jt = 0; jt < 4; ++jt)
      #pragma unroll
      for (int r = 0; r < 4; ++r)
        fgs[quad*4 + r][w*64 + jt*16 + m16] = __float2bfloat16(acc[jt][r]);
  }
  __syncthreads();

  // ---- phase E: rel = fused @ Wp + bp; wave w -> cols w*16..w*16+15 ----
  {
    int c = w*16 + m16;
    float bv = (c < 60) ? a.bp[c] : 0.f;
    f32x4 acc = (f32x4){bv, bv, bv, bv};
    #pragma unroll
    for (int ks = 0; ks < 8; ++ks) {
      short8 af = *(const short8*)((const char*)fgs +
                      (size_t)m16*528 + (ks*32 + ko)*2);
      short8 bf = *reinterpret_cast<const short8*>(
          a.WpP + (((size_t)w*8 + ks)*64 + lane)*8);
      acc = __builtin_amdgcn_mfma_f32_16x16x32_bf16(af, bf, acc, 0, 0, 0);
    }
    if (quad == 0) {
      #pragma unroll
      for (int r = 0; r < 4; ++r) {
        rl[r][c] = acc[r];
        if (c < 60) a.out[(size_t)(bn0 + r)*60 + c] = acc[r];
      }
    }
  }
  __syncthreads();
  if (tid < 8) {
    int lr = tid >> 1, xy = tid & 1;
    int grow = bn0 + lr;
    float run = a.centers[(size_t)(grow*PREVN + 5)*2 + xy];
    #pragma unroll
    for (int p = 0; p < PREDN; ++p) {
      run += rl[lr][2*p + xy];
      a.out[61440 + (size_t)grow*60 + 2*p + xy] = run;
    }
  }
}

extern "C" void kernel_launch(void* const* d_in, const int* in_sizes, int n_in,
                              void* d_out, int out_size, void* d_ws, size_t ws_size,
                              hipStream_t stream) {
  const float* centers = (const float*)d_in[0];
  float* ws = (float*)d_ws;
  __hip_bfloat16* wb = (__hip_bfloat16*)(ws + F32_END);
  __hip_bfloat16* xrs = (__hip_bfloat16*)(ws + OFF_XRS);
  float* incraw = (float*)(wb + BO_INC);

  const float* W_traj = (const float*)d_in[3];
  const float* b_traj = (const float*)d_in[4];
  const float* n2e_b1 = (const float*)d_in[6];
  const float* n2e_b2 = (const float*)d_in[8];
  const float* n2e_g  = (const float*)d_in[9];
  const float* n2e_be = (const float*)d_in[10];
  const float* e2n_b1 = (const float*)d_in[12];
  const float* e2n_b2 = (const float*)d_in[14];
  const float* e2n_g  = (const float*)d_in[15];
  const float* e2n_be = (const float*)d_in[16];
  const float* b_fuse = (const float*)d_in[18];
  const float* b_pred = (const float*)d_in[20];

  PrepArgs pa;
  pa.centers = centers; pa.W_traj = W_traj; pa.b_traj = b_traj;
  pa.n2e_W1 = (const float*)d_in[5];  pa.n2e_W2 = (const float*)d_in[7];
  pa.e2n_W1 = (const float*)d_in[11]; pa.e2n_W2 = (const float*)d_in[13];
  pa.W_fuse = (const float*)d_in[17]; pa.W_pred = (const float*)d_in[19];
  pa.ws = ws; pa.inc = incraw;
  pa.p1e = wb + BO_W1TE; pa.p2e = wb + BO_W2TE;
  pa.p1n = wb + BO_W1TN; pa.p2n = wb + BO_W2TN;
  pa.pf = wb + BO_WFT;   pa.pp = wb + BO_WPT;
  pa.xg = wb + BO_XG;

  k_prep<<<400, 256, 0, stream>>>(pa);
  k_xrs2<<<512, 64, 0, stream>>>(wb + BO_XG, wb + BO_W1TE, n2e_b1, xrs);
  k_mlp8<<<EROWS/64, 256, 0, stream>>>(xrs, wb + BO_W2TE, n2e_b2, wb + BO_E2,
                                       ws + OFF_STATS_E, incraw);
  NodeArgs na;
  na.e2 = wb + BO_E2; na.incraw = incraw;
  na.stE = ws + OFF_STATS_E; na.gamE = n2e_g; na.betE = n2e_be;
  na.W1P = wb + BO_W1TN; na.b1 = e2n_b1;
  na.W2P = wb + BO_W2TN; na.b2 = e2n_b2;
  na.stM = ws + OFF_STATS_M; na.gamM = e2n_g; na.betM = e2n_be;
  na.WfP = wb + BO_WFT; na.bfv = b_fuse;
  na.WpP = wb + BO_WPT; na.bp = b_pred;
  na.xg = wb + BO_XG; na.centers = centers;
  na.cnt = (unsigned int*)(ws + OFF_CNT);
  na.out = (float*)d_out;
  k_node<<<256, 256, 0, stream>>>(na);
}